// Round 1
// baseline (645.489 us; speedup 1.0000x reference)
//
#include <hip/hip_runtime.h>

#define B_    128
#define NELEC 192
#define NAO   128
#define NMO   96
#define NCONF 32
#define L_    80

__global__ void zero_out_k(float* out) { out[threadIdx.x] = 0.f; }

// G[b][s][m] = sum_n ao[b][2s][n] * mo_w[m][n]   (fp32, G is 128x96x96)
__global__ __launch_bounds__(256) void gemm_g_k(const float* __restrict__ ao,
                                                const float* __restrict__ mo_w,
                                                float* __restrict__ G) {
    int b  = blockIdx.x;          // 128
    int st = blockIdx.y;          // 6 tiles of 16 s-rows
    int tid = threadIdx.x;
    int s_local = tid >> 4;       // 0..15
    int m0 = (tid & 15) * 6;      // 0,6,...,90
    int s = st * 16 + s_local;    // 0..95
    const float* arow = ao + ((size_t)b * NELEC + 2 * s) * NAO;
    const float* w0   = mo_w + (size_t)m0 * NAO;
    float acc[6] = {0.f, 0.f, 0.f, 0.f, 0.f, 0.f};
    for (int n = 0; n < NAO; n += 4) {
        float4 av = *(const float4*)(arow + n);
#pragma unroll
        for (int q = 0; q < 6; ++q) {
            float4 wv = *(const float4*)(w0 + (size_t)q * NAO + n);
            acc[q] += av.x * wv.x + av.y * wv.y + av.z * wv.z + av.w * wv.w;
        }
    }
    float* grow = G + ((size_t)b * NMO + s) * NMO + m0;
#pragma unroll
    for (int q = 0; q < 6; ++q) grow[q] = acc[q];
}

// One block per (config c, batch b): gather 80x80, LU w/ partial pivoting, det.
template <bool USE_G>
__global__ __launch_bounds__(256) void det_k(const float* __restrict__ ao,
                                             const float* __restrict__ mo_w,
                                             const float* __restrict__ G,
                                             const float* __restrict__ ci_w,
                                             const int* __restrict__ conf_idx,
                                             float* __restrict__ out) {
    __shared__ float M[L_][81];          // stride 81: odd*17 bank step -> conflict-free columns
    __shared__ int   s_idx[L_];
    __shared__ unsigned long long red[4];

    int c = blockIdx.x;   // 32
    int b = blockIdx.y;   // 128
    int tid = threadIdx.x;
    int lane = tid & 63, wave = tid >> 6;

    if (tid < L_) s_idx[tid] = conf_idx[c * L_ + tid] >> 1;   // conf = 2*spatial
    __syncthreads();

    if (USE_G) {
        const float* Gb = G + (size_t)b * NMO * NMO;
        for (int e = tid; e < L_ * L_; e += 256) {
            int i = e / L_, j = e - i * L_;
            M[i][j] = Gb[(size_t)s_idx[i] * NMO + s_idx[j]];
        }
    } else {
        // ws-free fallback: M[i][j] = dot(ao[b, 2*s_i, :], mo_w[s_j, :])
        for (int e = tid; e < L_ * L_; e += 256) {
            int i = e / L_, j = e - i * L_;
            const float* arow = ao + ((size_t)b * NELEC + 2 * s_idx[i]) * NAO;
            const float* wrow = mo_w + (size_t)s_idx[j] * NAO;
            float acc = 0.f;
            for (int n = 0; n < NAO; n += 4) {
                float4 av = *(const float4*)(arow + n);
                float4 wv = *(const float4*)(wrow + n);
                acc += av.x * wv.x + av.y * wv.y + av.z * wv.z + av.w * wv.w;
            }
            M[i][j] = acc;
        }
    }
    __syncthreads();

    double det = 1.0;
    for (int k = 0; k < L_; ++k) {
        // ---- pivot search over rows k..79 of column k (packed float|idx, u64 max)
        int nr = L_ - k;
        unsigned long long key = 0ull;
        if (tid < nr) {
            float v = fabsf(M[k + tid][k]);
            key = ((unsigned long long)__float_as_uint(v) << 32) | (unsigned)(k + tid);
        }
#pragma unroll
        for (int off = 32; off; off >>= 1) {
            unsigned long long o = __shfl_xor(key, off);
            if (o > key) key = o;
        }
        if (lane == 0) red[wave] = key;
        __syncthreads();
        unsigned long long best = red[0];
        if (red[1] > best) best = red[1];
        if (red[2] > best) best = red[2];
        if (red[3] > best) best = red[3];
        int p = (int)(best & 0xffffffffu);

        // ---- swap rows k<->p (only cols >= k matter for det)
        if (p != k) {
            for (int j = k + tid; j < L_; j += 256) {
                float t = M[k][j]; M[k][j] = M[p][j]; M[p][j] = t;
            }
            det = -det;     // every thread flips consistently
        }
        __syncthreads();

        float piv = M[k][k];
        det *= (double)piv;

        // ---- rank-1 update: one row per thread, multiplier stays in register
        int i = k + 1 + tid;
        if (i < L_ && piv != 0.f) {
            float l = M[i][k] / piv;
            for (int j = k + 1; j < L_; ++j)
                M[i][j] -= l * M[k][j];
        }
        __syncthreads();
    }

    if (tid == 0)
        atomicAdd(&out[b], (float)(det * (double)ci_w[c]));
}

extern "C" void kernel_launch(void* const* d_in, const int* in_sizes, int n_in,
                              void* d_out, int out_size, void* d_ws, size_t ws_size,
                              hipStream_t stream) {
    const float* ao    = (const float*)d_in[0];   // (128,192,128) f32
    const float* mo_w  = (const float*)d_in[1];   // (96,128) f32
    const float* ci_w  = (const float*)d_in[2];   // (1,32) f32
    const int*   conf  = (const int*)d_in[3];     // (32,80) i32
    float* out = (float*)d_out;                   // (128,1) f32
    float* G   = (float*)d_ws;

    zero_out_k<<<dim3(1), dim3(B_), 0, stream>>>(out);

    const size_t g_need = (size_t)B_ * NMO * NMO * sizeof(float);  // 4.72 MB
    if (ws_size >= g_need) {
        gemm_g_k<<<dim3(B_, 6), dim3(256), 0, stream>>>(ao, mo_w, G);
        det_k<true><<<dim3(NCONF, B_), dim3(256), 0, stream>>>(ao, mo_w, G, ci_w, conf, out);
    } else {
        det_k<false><<<dim3(NCONF, B_), dim3(256), 0, stream>>>(ao, mo_w, nullptr, ci_w, conf, out);
    }
}

// Round 3
// 600.344 us; speedup vs baseline: 1.0752x; 1.0752x over previous
//
#include <hip/hip_runtime.h>

#define B_    128
#define NELEC 192
#define NAO   128
#define NMO   96
#define NCONF 32
#define L_    80

__global__ void zero_out_k(float* out) { if (threadIdx.x < B_) out[threadIdx.x] = 0.f; }

// G[b][s][m] = sum_n ao[b][2s][n] * mo_w[m][n]   (fp32, G is 128x96x96)
__global__ __launch_bounds__(256) void gemm_g_k(const float* __restrict__ ao,
                                                const float* __restrict__ mo_w,
                                                float* __restrict__ G) {
    int b  = blockIdx.x;          // 128
    int st = blockIdx.y;          // 6 tiles of 16 s-rows
    int tid = threadIdx.x;
    int s_local = tid >> 4;       // 0..15
    int m0 = (tid & 15) * 6;      // 0,6,...,90
    int s = st * 16 + s_local;    // 0..95
    const float* arow = ao + ((size_t)b * NELEC + 2 * s) * NAO;
    const float* w0   = mo_w + (size_t)m0 * NAO;
    float acc[6] = {0.f, 0.f, 0.f, 0.f, 0.f, 0.f};
    for (int n = 0; n < NAO; n += 4) {
        float4 av = *(const float4*)(arow + n);
#pragma unroll
        for (int q = 0; q < 6; ++q) {
            float4 wv = *(const float4*)(w0 + (size_t)q * NAO + n);
            acc[q] += av.x * wv.x + av.y * wv.y + av.z * wv.z + av.w * wv.w;
        }
    }
    float* grow = G + ((size_t)b * NMO + s) * NMO + m0;
#pragma unroll
    for (int q = 0; q < 6; ++q) grow[q] = acc[q];
}

__device__ __forceinline__ float rdlane(float x, int src) {
    return __int_as_float(__builtin_amdgcn_readlane(__float_as_int(x), src));
}

// One WAVE per (config c, batch b). Rows register-resident:
// lane l owns row l (array a); lanes 0..15 also own row 64+l (array bb).
// Shift-register LU: step k does a[t] = a[t+1] - l*u[t], so the live pivot
// column is always a[0] => all register indices compile-time static (rule #20).
// Pivot-row broadcast via v_readlane (SGPR operand to the FMA) - no LDS pipe.
// Pivoting by selection (no row swap); sign from inversion count via ballots.
template <bool USE_G>
__global__ __launch_bounds__(64) void det_reg_k(const float* __restrict__ ao,
                                                const float* __restrict__ mo_w,
                                                const float* __restrict__ G,
                                                const float* __restrict__ ci_w,
                                                const int* __restrict__ conf_idx,
                                                float* __restrict__ out) {
    __shared__ float Ms[40][84];     // transient transpose buffer (13.4 KB)
    __shared__ int   sIdx[L_];

    int c = blockIdx.x;   // 32
    int b = blockIdx.y;   // 128
    int lane = threadIdx.x;

    if (lane < 64) sIdx[lane] = conf_idx[c * L_ + lane] >> 1;        // conf = 2*spatial
    if (lane < 16) sIdx[64 + lane] = conf_idx[c * L_ + 64 + lane] >> 1;
    __syncthreads();

    float a[81], bb[81];
#pragma unroll
    for (int t = 0; t < 81; ++t) { a[t] = 0.f; bb[t] = 0.f; }

    const float* Gb = G + (size_t)b * NMO * NMO;

    // Gather M[i][j] = G[b][s_i][s_j] in two 40-row passes: coalesced-ish
    // global reads -> LDS, then per-lane row readout (float4).
#pragma unroll
    for (int pass = 0; pass < 2; ++pass) {
        int r0 = pass * 40;
        for (int e = lane; e < 40 * L_; e += 64) {
            int i = e / L_, j = e - i * L_;
            float v;
            if (USE_G) {
                v = Gb[(size_t)sIdx[r0 + i] * NMO + sIdx[j]];
            } else {
                const float* ar = ao + ((size_t)b * NELEC + 2 * sIdx[r0 + i]) * NAO;
                const float* wr = mo_w + (size_t)sIdx[j] * NAO;
                float acc = 0.f;
                for (int n = 0; n < NAO; n += 4) {
                    float4 av = *(const float4*)(ar + n);
                    float4 wv = *(const float4*)(wr + n);
                    acc += av.x * wv.x + av.y * wv.y + av.z * wv.z + av.w * wv.w;
                }
                v = acc;
            }
            Ms[i][j] = v;
        }
        __syncthreads();
        if (pass == 0) {
            if (lane < 40) {
#pragma unroll
                for (int tb = 0; tb < 20; ++tb) {
                    float4 v4 = *(const float4*)&Ms[lane][4 * tb];
                    a[4 * tb]     = v4.x; a[4 * tb + 1] = v4.y;
                    a[4 * tb + 2] = v4.z; a[4 * tb + 3] = v4.w;
                }
            }
        } else {
            if (lane >= 40) {
#pragma unroll
                for (int tb = 0; tb < 20; ++tb) {
                    float4 v4 = *(const float4*)&Ms[lane - 40][4 * tb];
                    a[4 * tb]     = v4.x; a[4 * tb + 1] = v4.y;
                    a[4 * tb + 2] = v4.z; a[4 * tb + 3] = v4.w;
                }
            }
            if (lane < 16) {
#pragma unroll
                for (int tb = 0; tb < 20; ++tb) {
                    float4 v4 = *(const float4*)&Ms[24 + lane][4 * tb];
                    bb[4 * tb]     = v4.x; bb[4 * tb + 1] = v4.y;
                    bb[4 * tb + 2] = v4.z; bb[4 * tb + 3] = v4.w;
                }
            }
        }
        __syncthreads();
    }

    double det = 1.0;
    int inv = 0;
    bool act_a = true;            // row `lane` still active
    bool act_b = (lane < 16);     // row 64+lane still active

    for (int k = 0; k < L_; ++k) {
        // ---- pivot search: max |col-k| over active rows (col k == a[0]/bb[0])
        float va = act_a ? fabsf(a[0])  : -1.f;
        float vb = act_b ? fabsf(bb[0]) : -1.f;
        float v = fmaxf(va, vb);
#pragma unroll
        for (int off = 32; off; off >>= 1) v = fmaxf(v, __shfl_xor(v, off));
        unsigned long long ma = __ballot(va == v);
        int p;
        if (ma) p = __ffsll(ma) - 1;
        else    p = 64 + __ffsll(__ballot(vb == v)) - 1;

        // ---- permutation parity: previously-retired rows with index > p
        inv += __popcll(__ballot(!act_a && lane > p));
        inv += __popcll(__ballot(lane < 16 && !act_b && (64 + lane) > p));

        float piv = (p < 64) ? rdlane(a[0], p) : rdlane(bb[0], p - 64);
        det *= (double)piv;

        if (lane == p)      act_a = false;   // retire pivot row BEFORE l-calc
        if (lane + 64 == p) act_b = false;

        float la = (act_a && piv != 0.f) ? a[0]  / piv : 0.f;
        float lb = (act_b && piv != 0.f) ? bb[0] / piv : 0.f;

        // ---- fused shift + rank-1 update; uniform coarse guard (blocks of 16)
        int rem = 79 - k;
        if (p < 64) {
#pragma unroll
            for (int tb = 0; tb < 5; ++tb) {
                if (tb * 16 <= rem) {
#pragma unroll
                    for (int tt = 0; tt < 16; ++tt) {
                        int t = tb * 16 + tt;
                        float u = rdlane(a[t + 1], p);
                        a[t]  = fmaf(-la, u, a[t + 1]);
                        bb[t] = fmaf(-lb, u, bb[t + 1]);
                    }
                }
            }
        } else {
            int ps = p - 64;
#pragma unroll
            for (int tb = 0; tb < 5; ++tb) {
                if (tb * 16 <= rem) {
#pragma unroll
                    for (int tt = 0; tt < 16; ++tt) {
                        int t = tb * 16 + tt;
                        float u = rdlane(bb[t + 1], ps);
                        a[t]  = fmaf(-la, u, a[t + 1]);
                        bb[t] = fmaf(-lb, u, bb[t + 1]);
                    }
                }
            }
        }
    }

    if (lane == 0) {
        float sgn = (inv & 1) ? -1.f : 1.f;
        atomicAdd(&out[b], (float)(det * (double)sgn * (double)ci_w[c]));
    }
}

extern "C" void kernel_launch(void* const* d_in, const int* in_sizes, int n_in,
                              void* d_out, int out_size, void* d_ws, size_t ws_size,
                              hipStream_t stream) {
    const float* ao    = (const float*)d_in[0];   // (128,192,128) f32
    const float* mo_w  = (const float*)d_in[1];   // (96,128) f32
    const float* ci_w  = (const float*)d_in[2];   // (1,32) f32
    const int*   conf  = (const int*)d_in[3];     // (32,80) i32
    float* out = (float*)d_out;                   // (128,1) f32
    float* G   = (float*)d_ws;

    zero_out_k<<<dim3(1), dim3(B_), 0, stream>>>(out);

    const size_t g_need = (size_t)B_ * NMO * NMO * sizeof(float);  // 4.72 MB
    if (ws_size >= g_need) {
        gemm_g_k<<<dim3(B_, 6), dim3(256), 0, stream>>>(ao, mo_w, G);
        det_reg_k<true><<<dim3(NCONF, B_), dim3(64), 0, stream>>>(ao, mo_w, G, ci_w, conf, out);
    } else {
        det_reg_k<false><<<dim3(NCONF, B_), dim3(64), 0, stream>>>(ao, mo_w, nullptr, ci_w, conf, out);
    }
}

// Round 5
// 349.003 us; speedup vs baseline: 1.8495x; 1.7202x over previous
//
#include <hip/hip_runtime.h>

#define B_    128
#define NELEC 192
#define NAO   128
#define NMO   96
#define NCONF 32
#define L_    80

__global__ void zero_out_k(float* out) { if (threadIdx.x < B_) out[threadIdx.x] = 0.f; }

// G[b][s][m] = sum_n ao[b][2s][n] * mo_w[m][n]   (fp32, G is 128x96x96)
__global__ __launch_bounds__(256) void gemm_g_k(const float* __restrict__ ao,
                                                const float* __restrict__ mo_w,
                                                float* __restrict__ G) {
    int b  = blockIdx.x;
    int st = blockIdx.y;
    int tid = threadIdx.x;
    int s_local = tid >> 4;
    int m0 = (tid & 15) * 6;
    int s = st * 16 + s_local;
    const float* arow = ao + ((size_t)b * NELEC + 2 * s) * NAO;
    const float* w0   = mo_w + (size_t)m0 * NAO;
    float acc[6] = {0.f, 0.f, 0.f, 0.f, 0.f, 0.f};
    for (int n = 0; n < NAO; n += 4) {
        float4 av = *(const float4*)(arow + n);
#pragma unroll
        for (int q = 0; q < 6; ++q) {
            float4 wv = *(const float4*)(w0 + (size_t)q * NAO + n);
            acc[q] += av.x * wv.x + av.y * wv.y + av.z * wv.z + av.w * wv.w;
        }
    }
    float* grow = G + ((size_t)b * NMO + s) * NMO + m0;
#pragma unroll
    for (int q = 0; q < 6; ++q) grow[q] = acc[q];
}

__device__ __forceinline__ float rdlane(float x, int src) {
    return __int_as_float(__builtin_amdgcn_readlane(__float_as_int(x), src));
}
__device__ __forceinline__ int rdlanei(int x, int src) {
    return __builtin_amdgcn_readlane(x, src);
}
// one stage of a DPP max-reduce (VALU pipe, not LDS)
#define DPPMAX(v, ctrl)                                                          \
    v = fmaxf(v, __int_as_float(__builtin_amdgcn_update_dpp(                     \
            __float_as_int(v), __float_as_int(v), (ctrl), 0xf, 0xf, false)))

// One WAVE per (config c, batch b).
// Lane l owns row l in registers (shift-LU: live pivot col is always a[0],
// all reg indices static). Rows 64..79 live in LDS (also shift-stored),
// updated by guardian lanes 0..15 with float4 quad windows.
// Phase 1 (k<16): pivots restricted to the 64 reg rows (threshold pivoting).
// Compaction: 48 reg + 16 LDS actives -> one row/lane via __shfl.
// Phase 2: pure-register LU over 64 lanes.
// Pivot search: DPP max reduce + ballot argmax. Sign: inversion-count ballots.
template <bool USE_G>
__global__ __launch_bounds__(64, 3) void det_reg_k(const float* __restrict__ ao,
                                                   const float* __restrict__ mo_w,
                                                   const float* __restrict__ G,
                                                   const float* __restrict__ ci_w,
                                                   const int* __restrict__ conf_idx,
                                                   float* __restrict__ out) {
    __shared__ __align__(16) float Ms[40][84];   // staging; rows 24..39 persist as B rows 64..79
    __shared__ int sIdx[L_];
    __shared__ int tbl[64];

    int c = blockIdx.x;   // 32
    int b = blockIdx.y;   // 128
    int lane = threadIdx.x;

    if (lane < 64) sIdx[lane] = conf_idx[c * L_ + lane] >> 1;
    if (lane < 16) sIdx[64 + lane] = conf_idx[c * L_ + 64 + lane] >> 1;
    __syncthreads();

    float a[81];
#pragma unroll
    for (int t = 0; t < 81; ++t) a[t] = 0.f;

    const float* Gb = G + (size_t)b * NMO * NMO;

    // ---- gather: pass 0 stages rows 0..39 (readout lanes 0..39);
    //      pass 1 stages rows 40..79 (readout lanes 40..63; Ms[24..39] = LDS rows 64..79)
#pragma unroll 1
    for (int pass = 0; pass < 2; ++pass) {
        int r0 = pass * 40;
        for (int e = lane; e < 40 * L_; e += 64) {
            int i = e / L_, j = e - i * L_;
            float v;
            if (USE_G) {
                v = Gb[(size_t)sIdx[r0 + i] * NMO + sIdx[j]];
            } else {
                const float* ar = ao + ((size_t)b * NELEC + 2 * sIdx[r0 + i]) * NAO;
                const float* wr = mo_w + (size_t)sIdx[j] * NAO;
                float acc = 0.f;
                for (int n = 0; n < NAO; n += 4) {
                    float4 av = *(const float4*)(ar + n);
                    float4 wv = *(const float4*)(wr + n);
                    acc += av.x * wv.x + av.y * wv.y + av.z * wv.z + av.w * wv.w;
                }
                v = acc;
            }
            Ms[i][j] = v;
        }
        __syncthreads();
        if (pass == 0) {
            if (lane < 40) {
#pragma unroll
                for (int q = 0; q < 20; ++q) {
                    float4 v4 = *(const float4*)&Ms[lane][4 * q];
                    a[4 * q] = v4.x; a[4 * q + 1] = v4.y; a[4 * q + 2] = v4.z; a[4 * q + 3] = v4.w;
                }
            }
        } else {
            if (lane >= 40) {
#pragma unroll
                for (int q = 0; q < 20; ++q) {
                    float4 v4 = *(const float4*)&Ms[lane - 40][4 * q];
                    a[4 * q] = v4.x; a[4 * q + 1] = v4.y; a[4 * q + 2] = v4.z; a[4 * q + 3] = v4.w;
                }
            }
        }
        __syncthreads();
    }

    double det = 1.0;
    int inv = 0;
    bool act = true;      // reg row active
    // phase-1 reg rowid == lane; LDS-row ids 64..79 (never pivots, never < pr)

    // ---------------- phase 1: k = 0..15 ----------------
#pragma unroll 1
    for (int k = 0; k < 16; ++k) {
        int rem = 79 - k;
        float cand = act ? fabsf(a[0]) : -1.f;
        float m = cand;
        DPPMAX(m, 0x111); DPPMAX(m, 0x112); DPPMAX(m, 0x114); DPPMAX(m, 0x118);
        DPPMAX(m, 0x142); DPPMAX(m, 0x143);
        float mx = rdlane(m, 63);
        unsigned long long sel = __ballot(act && cand == mx);
        int p = __ffsll(sel) - 1;

        inv += __popcll(__ballot(act && lane < p));

        float piv = rdlane(a[0], p);
        det *= (double)piv;
        if (lane == p) act = false;
        float la = (act && piv != 0.f) ? a[0] / piv : 0.f;

        // ---- LDS B-row shift-update (guardians, quad window; all idx static)
        if (lane < 16) {
            float* Brow = &Ms[24 + lane][0];
            float4 Qc = *(const float4*)&Brow[0];
            float lb = (piv != 0.f) ? Qc.x / piv : 0.f;
#pragma unroll
            for (int tb = 0; tb < 5; ++tb) {
                if (16 * tb < rem) {
#pragma unroll
                    for (int j = 0; j < 4; ++j) {
                        float4 Qn = *(const float4*)&Brow[16 * tb + 4 * j + 4];
                        float4 W;
                        W.x = fmaf(-lb, rdlane(a[16 * tb + 4 * j + 1], p), Qc.y);
                        W.y = fmaf(-lb, rdlane(a[16 * tb + 4 * j + 2], p), Qc.z);
                        W.z = fmaf(-lb, rdlane(a[16 * tb + 4 * j + 3], p), Qc.w);
                        W.w = fmaf(-lb, rdlane(a[16 * tb + 4 * j + 4], p), Qn.x);
                        *(float4*)&Brow[16 * tb + 4 * j] = W;
                        Qc = Qn;
                    }
                }
            }
        }

        // ---- register row shift-update (reads a[t+1] before it's overwritten)
#pragma unroll
        for (int tb = 0; tb < 5; ++tb) {
            if (16 * tb < rem) {
#pragma unroll
                for (int i = 0; i < 16; ++i) {
                    float u = rdlane(a[16 * tb + i + 1], p);
                    a[16 * tb + i] = fmaf(-la, u, a[16 * tb + i + 1]);
                }
            }
        }
    }

    // ---------------- compaction: 48 reg + 16 LDS actives -> 1 row/lane ----------------
    unsigned long long mask_a = __ballot(act);
    int rank = __popcll(mask_a & ((1ull << lane) - 1));
    if (act) tbl[rank] = lane;
    __syncthreads();
    int srcl = tbl[lane & 63];                 // valid for lane<48
    int src2 = (lane < 48) ? srcl : lane;
#pragma unroll
    for (int t = 0; t < 64; ++t) a[t] = __shfl(a[t], src2);
    if (lane >= 48) {
        const float* Brow = &Ms[24 + (lane - 48)][0];
#pragma unroll
        for (int q = 0; q < 16; ++q) {
            float4 v4 = *(const float4*)&Brow[4 * q];
            a[4 * q] = v4.x; a[4 * q + 1] = v4.y; a[4 * q + 2] = v4.z; a[4 * q + 3] = v4.w;
        }
    }
    int rowid = (lane < 48) ? srcl : (16 + lane);   // 64 + (lane-48)
    act = true;

    // ---------------- phase 2: k = 16..79 ----------------
#pragma unroll 1
    for (int k = 16; k < 80; ++k) {
        int rem = 79 - k;
        float cand = act ? fabsf(a[0]) : -1.f;
        float m = cand;
        DPPMAX(m, 0x111); DPPMAX(m, 0x112); DPPMAX(m, 0x114); DPPMAX(m, 0x118);
        DPPMAX(m, 0x142); DPPMAX(m, 0x143);
        float mx = rdlane(m, 63);
        unsigned long long sel = __ballot(act && cand == mx);
        int p = __ffsll(sel) - 1;

        int pr = rdlanei(rowid, p);
        inv += __popcll(__ballot(act && rowid < pr));

        float piv = rdlane(a[0], p);
        det *= (double)piv;
        if (lane == p) act = false;
        float la = (act && piv != 0.f) ? a[0] / piv : 0.f;

#pragma unroll
        for (int tb = 0; tb < 4; ++tb) {
            if (16 * tb < rem) {
#pragma unroll
                for (int i = 0; i < 16; ++i) {
                    float u = rdlane(a[16 * tb + i + 1], p);
                    a[16 * tb + i] = fmaf(-la, u, a[16 * tb + i + 1]);
                }
            }
        }
    }

    if (lane == 0) {
        double sgn = (inv & 1) ? -1.0 : 1.0;
        atomicAdd(&out[b], (float)(det * sgn * (double)ci_w[c]));
    }
}

extern "C" void kernel_launch(void* const* d_in, const int* in_sizes, int n_in,
                              void* d_out, int out_size, void* d_ws, size_t ws_size,
                              hipStream_t stream) {
    const float* ao    = (const float*)d_in[0];   // (128,192,128) f32
    const float* mo_w  = (const float*)d_in[1];   // (96,128) f32
    const float* ci_w  = (const float*)d_in[2];   // (1,32) f32
    const int*   conf  = (const int*)d_in[3];     // (32,80) i32
    float* out = (float*)d_out;                   // (128,1) f32
    float* G   = (float*)d_ws;

    zero_out_k<<<dim3(1), dim3(B_), 0, stream>>>(out);

    const size_t g_need = (size_t)B_ * NMO * NMO * sizeof(float);  // 4.72 MB
    if (ws_size >= g_need) {
        gemm_g_k<<<dim3(B_, 6), dim3(256), 0, stream>>>(ao, mo_w, G);
        det_reg_k<true><<<dim3(NCONF, B_), dim3(64), 0, stream>>>(ao, mo_w, G, ci_w, conf, out);
    } else {
        det_reg_k<false><<<dim3(NCONF, B_), dim3(64), 0, stream>>>(ao, mo_w, nullptr, ci_w, conf, out);
    }
}

// Round 6
// 321.355 us; speedup vs baseline: 2.0086x; 1.0860x over previous
//
#include <hip/hip_runtime.h>

#define B_    128
#define NELEC 192
#define NAO   128
#define NMO   96
#define NCONF 32
#define L_    80

__global__ void zero_out_k(float* out) { if (threadIdx.x < B_) out[threadIdx.x] = 0.f; }

// G[b][s][m] = sum_n ao[b][2s][n] * mo_w[m][n]   (fp32, G is 128x96x96)
__global__ __launch_bounds__(256) void gemm_g_k(const float* __restrict__ ao,
                                                const float* __restrict__ mo_w,
                                                float* __restrict__ G) {
    int b  = blockIdx.x;
    int st = blockIdx.y;
    int tid = threadIdx.x;
    int s_local = tid >> 4;
    int m0 = (tid & 15) * 6;
    int s = st * 16 + s_local;
    const float* arow = ao + ((size_t)b * NELEC + 2 * s) * NAO;
    const float* w0   = mo_w + (size_t)m0 * NAO;
    float acc[6] = {0.f, 0.f, 0.f, 0.f, 0.f, 0.f};
    for (int n = 0; n < NAO; n += 4) {
        float4 av = *(const float4*)(arow + n);
#pragma unroll
        for (int q = 0; q < 6; ++q) {
            float4 wv = *(const float4*)(w0 + (size_t)q * NAO + n);
            acc[q] += av.x * wv.x + av.y * wv.y + av.z * wv.z + av.w * wv.w;
        }
    }
    float* grow = G + ((size_t)b * NMO + s) * NMO + m0;
#pragma unroll
    for (int q = 0; q < 6; ++q) grow[q] = acc[q];
}

__device__ __forceinline__ float rdlane(float x, int src) {
    return __int_as_float(__builtin_amdgcn_readlane(__float_as_int(x), src));
}
__device__ __forceinline__ int rdlanei(int x, int src) {
    return __builtin_amdgcn_readlane(x, src);
}
// one stage of a DPP max-reduce (VALU pipe, not LDS)
#define DPPMAX(v, ctrl)                                                          \
    v = fmaxf(v, __int_as_float(__builtin_amdgcn_update_dpp(                     \
            __float_as_int(v), __float_as_int(v), (ctrl), 0xf, 0xf, false)))

// One WAVE per (config c, batch b).
// Lane l owns row l in registers (shift-LU: live pivot col is always a[0],
// all reg indices static). Rows 64..79 live in LDS (also shift-stored),
// updated by guardian lanes 0..15 with float4 quad windows.
// Phase 1 (k<16): pivots restricted to the 64 reg rows (threshold pivoting).
// Compaction: 48 reg + 16 LDS actives -> one row/lane via __shfl.
// Phase 2: pure-register LU over 64 lanes.
// Pivot search: DPP max reduce + ballot argmax. Sign: inversion-count ballots.
// NOTE: __launch_bounds__(64) ONLY — round-5 showed that (64,3) caps the
// allocator at ~168 VGPR, below the ~180 demand, and LLVM then spills the
// whole a[81] array to scratch (VGPR_Count=84, WRITE_SIZE 19.6MB, 237us).
template <bool USE_G>
__global__ __launch_bounds__(64) void det_reg_k(const float* __restrict__ ao,
                                                const float* __restrict__ mo_w,
                                                const float* __restrict__ G,
                                                const float* __restrict__ ci_w,
                                                const int* __restrict__ conf_idx,
                                                float* __restrict__ out) {
    __shared__ __align__(16) float Ms[40][84];   // staging; rows 24..39 persist as B rows 64..79
    __shared__ int sIdx[L_];
    __shared__ int tbl[64];

    int c = blockIdx.x;   // 32
    int b = blockIdx.y;   // 128
    int lane = threadIdx.x;

    if (lane < 64) sIdx[lane] = conf_idx[c * L_ + lane] >> 1;
    if (lane < 16) sIdx[64 + lane] = conf_idx[c * L_ + 64 + lane] >> 1;
    __syncthreads();

    float a[81];
#pragma unroll
    for (int t = 0; t < 81; ++t) a[t] = 0.f;

    const float* Gb = G + (size_t)b * NMO * NMO;

    // ---- gather: pass 0 stages rows 0..39 (readout lanes 0..39);
    //      pass 1 stages rows 40..79 (readout lanes 40..63; Ms[24..39] = LDS rows 64..79)
#pragma unroll 1
    for (int pass = 0; pass < 2; ++pass) {
        int r0 = pass * 40;
        for (int e = lane; e < 40 * L_; e += 64) {
            int i = e / L_, j = e - i * L_;
            float v;
            if (USE_G) {
                v = Gb[(size_t)sIdx[r0 + i] * NMO + sIdx[j]];
            } else {
                const float* ar = ao + ((size_t)b * NELEC + 2 * sIdx[r0 + i]) * NAO;
                const float* wr = mo_w + (size_t)sIdx[j] * NAO;
                float acc = 0.f;
                for (int n = 0; n < NAO; n += 4) {
                    float4 av = *(const float4*)(ar + n);
                    float4 wv = *(const float4*)(wr + n);
                    acc += av.x * wv.x + av.y * wv.y + av.z * wv.z + av.w * wv.w;
                }
                v = acc;
            }
            Ms[i][j] = v;
        }
        __syncthreads();
        if (pass == 0) {
            if (lane < 40) {
#pragma unroll
                for (int q = 0; q < 20; ++q) {
                    float4 v4 = *(const float4*)&Ms[lane][4 * q];
                    a[4 * q] = v4.x; a[4 * q + 1] = v4.y; a[4 * q + 2] = v4.z; a[4 * q + 3] = v4.w;
                }
            }
        } else {
            if (lane >= 40) {
#pragma unroll
                for (int q = 0; q < 20; ++q) {
                    float4 v4 = *(const float4*)&Ms[lane - 40][4 * q];
                    a[4 * q] = v4.x; a[4 * q + 1] = v4.y; a[4 * q + 2] = v4.z; a[4 * q + 3] = v4.w;
                }
            }
        }
        __syncthreads();
    }

    double det = 1.0;
    int inv = 0;
    bool act = true;      // reg row active
    // phase-1 reg rowid == lane; LDS-row ids 64..79 (never pivots, never < pr)

    // ---------------- phase 1: k = 0..15 ----------------
#pragma unroll 1
    for (int k = 0; k < 16; ++k) {
        int rem = 79 - k;
        float cand = act ? fabsf(a[0]) : -1.f;
        float m = cand;
        DPPMAX(m, 0x111); DPPMAX(m, 0x112); DPPMAX(m, 0x114); DPPMAX(m, 0x118);
        DPPMAX(m, 0x142); DPPMAX(m, 0x143);
        float mx = rdlane(m, 63);
        unsigned long long sel = __ballot(act && cand == mx);
        int p = __ffsll(sel) - 1;

        inv += __popcll(__ballot(act && lane < p));

        float piv = rdlane(a[0], p);
        det *= (double)piv;
        if (lane == p) act = false;
        float la = (act && piv != 0.f) ? a[0] / piv : 0.f;

        // ---- LDS B-row shift-update (guardians, quad window; all idx static)
        if (lane < 16) {
            float* Brow = &Ms[24 + lane][0];
            float4 Qc = *(const float4*)&Brow[0];
            float lb = (piv != 0.f) ? Qc.x / piv : 0.f;
#pragma unroll
            for (int tb = 0; tb < 5; ++tb) {
                if (16 * tb < rem) {
#pragma unroll
                    for (int j = 0; j < 4; ++j) {
                        float4 Qn = *(const float4*)&Brow[16 * tb + 4 * j + 4];
                        float4 W;
                        W.x = fmaf(-lb, rdlane(a[16 * tb + 4 * j + 1], p), Qc.y);
                        W.y = fmaf(-lb, rdlane(a[16 * tb + 4 * j + 2], p), Qc.z);
                        W.z = fmaf(-lb, rdlane(a[16 * tb + 4 * j + 3], p), Qc.w);
                        W.w = fmaf(-lb, rdlane(a[16 * tb + 4 * j + 4], p), Qn.x);
                        *(float4*)&Brow[16 * tb + 4 * j] = W;
                        Qc = Qn;
                    }
                }
            }
        }

        // ---- register row shift-update (reads a[t+1] before it's overwritten)
#pragma unroll
        for (int tb = 0; tb < 5; ++tb) {
            if (16 * tb < rem) {
#pragma unroll
                for (int i = 0; i < 16; ++i) {
                    float u = rdlane(a[16 * tb + i + 1], p);
                    a[16 * tb + i] = fmaf(-la, u, a[16 * tb + i + 1]);
                }
            }
        }
    }

    // ---------------- compaction: 48 reg + 16 LDS actives -> 1 row/lane ----------------
    unsigned long long mask_a = __ballot(act);
    int rank = __popcll(mask_a & ((1ull << lane) - 1));
    if (act) tbl[rank] = lane;
    __syncthreads();
    int srcl = tbl[lane & 63];                 // valid for lane<48
    int src2 = (lane < 48) ? srcl : lane;
#pragma unroll
    for (int t = 0; t < 64; ++t) a[t] = __shfl(a[t], src2);
    if (lane >= 48) {
        const float* Brow = &Ms[24 + (lane - 48)][0];
#pragma unroll
        for (int q = 0; q < 16; ++q) {
            float4 v4 = *(const float4*)&Brow[4 * q];
            a[4 * q] = v4.x; a[4 * q + 1] = v4.y; a[4 * q + 2] = v4.z; a[4 * q + 3] = v4.w;
        }
    }
    int rowid = (lane < 48) ? srcl : (16 + lane);   // 64 + (lane-48)
    act = true;

    // ---------------- phase 2: k = 16..79 ----------------
#pragma unroll 1
    for (int k = 16; k < 80; ++k) {
        int rem = 79 - k;
        float cand = act ? fabsf(a[0]) : -1.f;
        float m = cand;
        DPPMAX(m, 0x111); DPPMAX(m, 0x112); DPPMAX(m, 0x114); DPPMAX(m, 0x118);
        DPPMAX(m, 0x142); DPPMAX(m, 0x143);
        float mx = rdlane(m, 63);
        unsigned long long sel = __ballot(act && cand == mx);
        int p = __ffsll(sel) - 1;

        int pr = rdlanei(rowid, p);
        inv += __popcll(__ballot(act && rowid < pr));

        float piv = rdlane(a[0], p);
        det *= (double)piv;
        if (lane == p) act = false;
        float la = (act && piv != 0.f) ? a[0] / piv : 0.f;

#pragma unroll
        for (int tb = 0; tb < 4; ++tb) {
            if (16 * tb < rem) {
#pragma unroll
                for (int i = 0; i < 16; ++i) {
                    float u = rdlane(a[16 * tb + i + 1], p);
                    a[16 * tb + i] = fmaf(-la, u, a[16 * tb + i + 1]);
                }
            }
        }
    }

    if (lane == 0) {
        double sgn = (inv & 1) ? -1.0 : 1.0;
        atomicAdd(&out[b], (float)(det * sgn * (double)ci_w[c]));
    }
}

extern "C" void kernel_launch(void* const* d_in, const int* in_sizes, int n_in,
                              void* d_out, int out_size, void* d_ws, size_t ws_size,
                              hipStream_t stream) {
    const float* ao    = (const float*)d_in[0];   // (128,192,128) f32
    const float* mo_w  = (const float*)d_in[1];   // (96,128) f32
    const float* ci_w  = (const float*)d_in[2];   // (1,32) f32
    const int*   conf  = (const int*)d_in[3];     // (32,80) i32
    float* out = (float*)d_out;                   // (128,1) f32
    float* G   = (float*)d_ws;

    zero_out_k<<<dim3(1), dim3(B_), 0, stream>>>(out);

    const size_t g_need = (size_t)B_ * NMO * NMO * sizeof(float);  // 4.72 MB
    if (ws_size >= g_need) {
        gemm_g_k<<<dim3(B_, 6), dim3(256), 0, stream>>>(ao, mo_w, G);
        det_reg_k<true><<<dim3(NCONF, B_), dim3(64), 0, stream>>>(ao, mo_w, G, ci_w, conf, out);
    } else {
        det_reg_k<false><<<dim3(NCONF, B_), dim3(64), 0, stream>>>(ao, mo_w, nullptr, ci_w, conf, out);
    }
}